// Round 6
// baseline (150.363 us; speedup 1.0000x reference)
//
#include <hip/hip_runtime.h>

#define S_LEN 2048
#define E_DIM 1024
#define NH 16
#define HD 64
#define NT (S_LEN / 64)
// (1/sqrt(64)) * log2(e): fold softmax scale into log2 domain (applied to Q pre-cvt)
#define SCALE_L2E 0.18033688011112042f
#define DEFER_THR 8.0f

typedef __bf16 bf16;
typedef __attribute__((ext_vector_type(4))) bf16 bf16x4;
typedef __attribute__((ext_vector_type(8))) bf16 bf16x8;
typedef __attribute__((ext_vector_type(4))) float f32x4;
typedef unsigned long long u64;
typedef unsigned int u32;

#define MFMA(a, b, c) __builtin_amdgcn_mfma_f32_16x16x32_bf16((a), (b), (c), 0, 0, 0)

__device__ __forceinline__ bf16x8 cvt8(f32x4 a, f32x4 b) {
  bf16x8 r;
  r[0] = (bf16)a[0]; r[1] = (bf16)a[1]; r[2] = (bf16)a[2]; r[3] = (bf16)a[3];
  r[4] = (bf16)b[0]; r[5] = (bf16)b[1]; r[6] = (bf16)b[2]; r[7] = (bf16)b[3];
  return r;
}

__device__ __forceinline__ bf16x8 load_cvt_frag(const float* p) {
  f32x4 a = *(const f32x4*)(p);
  f32x4 b = *(const f32x4*)(p + 16);
  return cvt8(a, b);
}

// ---------------- K/V projection + fused mask bit-pack ----------------
// K/V outputs in MFMA-fragment-tiled order (16B/lane coalesced loads in attn).
// Mask packed TRANSPOSED: bits[colblk * S + row] so attn's per-wave mask-word
// load (16 consecutive rows, one colblk) is 128B contiguous.
__global__ __launch_bounds__(256) void kvproj_k(
    const float* __restrict__ Kin, const float* __restrict__ Vin,
    const float* __restrict__ Wk, const float* __restrict__ bk,
    const float* __restrict__ Wv, const float* __restrict__ bv,
    const int* __restrict__ mask,
    bf16* __restrict__ KpF, bf16* __restrict__ VpF, u64* __restrict__ bits) {
  const int xcd = blockIdx.x & 7;
  const int idx = blockIdx.x >> 3;           // 0..127
  const int bh = xcd * 4 + (idx >> 5);       // 4 heads per XCD
  const int sblk = idx & 31;                 // S/64 = 32
  const int h = bh & (NH - 1);
  const int b = bh >> 4;
  const int lane = threadIdx.x & 63;
  const int wave = threadIdx.x >> 6;
  const int g = lane >> 4;
  const int c16 = lane & 15;
  const int sbase = sblk * 64 + wave * 16;
  const int srow = sbase + c16;

  const float* xk = Kin + ((size_t)b * S_LEN + srow) * E_DIM + h * HD;
  const float* xv = Vin + ((size_t)b * S_LEN + srow) * E_DIM + h * HD;
  bf16x8 xkf[2], xvf[2];
#pragma unroll
  for (int c = 0; c < 2; ++c) {
    xkf[c] = load_cvt_frag(xk + 32 * c + 4 * g);
    xvf[c] = load_cvt_frag(xv + 32 * c + 4 * g);
  }

  // Kp = Xk * Wk^T + bk
#pragma unroll
  for (int nt = 0; nt < 4; ++nt) {
    const float* wr = Wk + (16 * nt + c16) * HD + 4 * g;
    f32x4 acc = {0.f, 0.f, 0.f, 0.f};
    acc = MFMA(xkf[0], load_cvt_frag(wr), acc);
    acc = MFMA(xkf[1], load_cvt_frag(wr + 32), acc);
    const float bias = bk[16 * nt + c16];
    const size_t fidx = (((size_t)bh * 32 + sblk) * 4 + wave) * 2 + (nt >> 1);
    const int e = (c16 & 3) + 4 * (nt & 1);
#pragma unroll
    for (int r = 0; r < 4; ++r) {
      const int lane_p = (c16 >> 2) * 16 + 4 * g + r;
      KpF[fidx * 512 + lane_p * 8 + e] = (bf16)(acc[r] + bias);
    }
  }
  // Vp (transposed): A = Wv rows=d_out, B = Xv^T
#pragma unroll
  for (int nt = 0; nt < 4; ++nt) {
    const float* wr = Wv + (16 * nt + c16) * HD + 4 * g;
    f32x4 acc = {0.f, 0.f, 0.f, 0.f};
    acc = MFMA(load_cvt_frag(wr), xvf[0], acc);
    acc = MFMA(load_cvt_frag(wr + 32), xvf[1], acc);
    const size_t fidx = (((size_t)bh * 32 + sblk) * 4 + nt) * 2 + (wave >> 1);
    const int e = (c16 & 3) + 4 * (wave & 1);
#pragma unroll
    for (int r = 0; r < 4; ++r) {
      const int dout = 16 * nt + 4 * g + r;
      const int lane_p = (c16 >> 2) * 16 + 4 * g + r;
      VpF[fidx * 512 + lane_p * 8 + e] = (bf16)(acc[r] + bv[dout]);
    }
  }

  // fused mask bit-pack: this block handles 64 words, 16 per wave
  const int wbase = blockIdx.x * 64 + wave * 16;
  int mv[16];
#pragma unroll
  for (int i = 0; i < 16; ++i) mv[i] = mask[(size_t)(wbase + i) * 64 + lane];
#pragma unroll
  for (int i = 0; i < 16; ++i) {
    const u64 bb = __ballot(mv[i] != 0);
    const int w = wbase + i;  // w = row*32 + colblk
    if (lane == 0) bits[(size_t)(w & 31) * S_LEN + (w >> 5)] = bb;
  }
}

// ---------------- attention: barrier-free, QK-pipelined flash ----------------
__global__ __launch_bounds__(256, 4) void attn_k(
    const float* __restrict__ Qin, const float* __restrict__ Wq, const float* __restrict__ bq,
    const bf16* __restrict__ KpF, const bf16* __restrict__ VpF,
    const u64* __restrict__ mbits, float* __restrict__ out) {
  const int xcd = blockIdx.x & 7;
  const int idx = blockIdx.x >> 3;
  const int bh = xcd * 4 + (idx >> 5);
  const int qblk = idx & 31;
  const int h = bh & (NH - 1);
  const int b = bh >> 4;
  const int lane = threadIdx.x & 63;
  const int wave = threadIdx.x >> 6;
  const int g = lane >> 4;
  const int c16 = lane & 15;
  const int qrow = qblk * 64 + wave * 16 + c16;  // each lane owns ONE q row

  // Q projection in-register; fold softmax scale into Q before bf16 cvt.
  const float* xq = Qin + ((size_t)b * S_LEN + qrow) * E_DIM + h * HD;
  bf16x8 xqf[2];
#pragma unroll
  for (int c = 0; c < 2; ++c) xqf[c] = load_cvt_frag(xq + 32 * c + 4 * g);
  f32x4 qt[4];
#pragma unroll
  for (int t = 0; t < 4; ++t) {
    const float* wr = Wq + (16 * t + c16) * HD + 4 * g;
    f32x4 acc = {0.f, 0.f, 0.f, 0.f};
    acc = MFMA(load_cvt_frag(wr), xqf[0], acc);
    acc = MFMA(load_cvt_frag(wr + 32), xqf[1], acc);
#pragma unroll
    for (int r = 0; r < 4; ++r) acc[r] = (acc[r] + bq[16 * t + 4 * g + r]) * SCALE_L2E;
    qt[t] = acc;
  }
  bf16x8 qfrag[2];
#pragma unroll
  for (int c = 0; c < 2; ++c) qfrag[c] = cvt8(qt[2 * c], qt[2 * c + 1]);

  // constant all-ones A-fragment: o5 = MFMA(ones, pfrag) accumulates sum(P) per q col
  bf16x8 ones;
#pragma unroll
  for (int i = 0; i < 8; ++i) ones[i] = (bf16)1.0f;

  // per-lane fragment bases (16B/lane, fully coalesced)
  const bf16* ktl = KpF + ((size_t)bh * 32) * 4096 + lane * 8;  // + kb*4096 + f*512
  const bf16* vtl = VpF + ((size_t)bh * 32) * 4096 + lane * 8;
  const u64* mrowT = mbits + qrow;                              // + kb*S_LEN

  float m = -1e30f;
  f32x4 o[4] = {};
  f32x4 o5 = {};

  bf16x8 kf[8], vfr[8];
  u64 mwa, mwb;
  f32x4 st[4];  // scores of the CURRENT tile (computed one step ahead)

  // prologue: K(0)+mask(0), then QK(0)
#pragma unroll
  for (int f = 0; f < 8; ++f) kf[f] = *(const bf16x8*)(ktl + f * 512);
  mwa = mrowT[0];
#pragma unroll
  for (int ks = 0; ks < 4; ++ks) {
    f32x4 acc = {0.f, 0.f, 0.f, 0.f};
    acc = MFMA(kf[2 * ks], qfrag[0], acc);
    acc = MFMA(kf[2 * ks + 1], qfrag[1], acc);
    st[ks] = acc;
  }

  // STEP(t): loads K(t+1)/mask(t+1)/V(t); softmax(t) on st; QK(t+1) -> st; PV(t)
#define STEP(MWC, MWN, KBT)                                                       \
  {                                                                               \
    const int nk1 = ((KBT) + 1 < NT) ? (KBT) + 1 : NT - 1;                        \
    _Pragma("unroll") for (int f = 0; f < 8; ++f)                                 \
        kf[f] = *(const bf16x8*)(ktl + (size_t)nk1 * 4096 + f * 512);             \
    MWN = mrowT[(size_t)nk1 * S_LEN];                                             \
    _Pragma("unroll") for (int f = 0; f < 8; ++f)                                 \
        vfr[f] = *(const bf16x8*)(vtl + (size_t)(KBT) * 4096 + f * 512);          \
    /* softmax(t): max3-friendly tree over raw scores (upper bound, safe) */      \
    const float t0 = fmaxf(fmaxf(st[0][0], st[0][1]), st[0][2]);                  \
    const float t1 = fmaxf(fmaxf(st[0][3], st[1][0]), st[1][1]);                  \
    const float t2 = fmaxf(fmaxf(st[1][2], st[1][3]), st[2][0]);                  \
    const float t3 = fmaxf(fmaxf(st[2][1], st[2][2]), st[2][3]);                  \
    const float t4 = fmaxf(fmaxf(st[3][0], st[3][1]), st[3][2]);                  \
    const float tm =                                                              \
        fmaxf(fmaxf(fmaxf(t0, t1), t2), fmaxf(fmaxf(t3, t4), st[3][3]));          \
    if (!__all(tm <= m + DEFER_THR)) {                                            \
      float tmax = fmaxf(tm, __shfl_xor(tm, 16));                                 \
      tmax = fmaxf(tmax, __shfl_xor(tmax, 32));                                   \
      const float mnew = fmaxf(m, tmax);                                          \
      const float corr = __builtin_amdgcn_exp2f(m - mnew);                        \
      _Pragma("unroll") for (int t = 0; t < 4; ++t)                               \
          _Pragma("unroll") for (int r = 0; r < 4; ++r) o[t][r] *= corr;          \
      _Pragma("unroll") for (int r = 0; r < 4; ++r) o5[r] *= corr;                \
      m = mnew;                                                                   \
    }                                                                             \
    const u64 mws = (MWC) >> (4 * g);                                             \
    const u32 mlo = (u32)mws;                                                     \
    const u32 mhi = (u32)(mws >> 32);                                             \
    _Pragma("unroll") for (int ks = 0; ks < 4; ++ks) {                            \
      const u32 mword = (ks < 2) ? mlo : mhi;                                     \
      const int base = (ks & 1) * 16;                                             \
      _Pragma("unroll") for (int r = 0; r < 4; ++r) {                             \
        const float p = __builtin_amdgcn_exp2f(st[ks][r] - m);                    \
        const int keep = __builtin_amdgcn_sbfe(mword, base + r, 1);               \
        st[ks][r] = __uint_as_float(__float_as_uint(p) & (u32)keep);              \
      }                                                                           \
    }                                                                             \
    const bf16x8 pfrag0 = cvt8(st[0], st[1]);                                     \
    const bf16x8 pfrag1 = cvt8(st[2], st[3]);                                     \
    __builtin_amdgcn_s_setprio(1);                                                \
    /* QK(t+1) into freed st; max(t+1) won't need it until next step */           \
    _Pragma("unroll") for (int ks = 0; ks < 4; ++ks) {                            \
      f32x4 acc = {0.f, 0.f, 0.f, 0.f};                                           \
      acc = MFMA(kf[2 * ks], qfrag[0], acc);                                      \
      acc = MFMA(kf[2 * ks + 1], qfrag[1], acc);                                  \
      st[ks] = acc;                                                               \
    }                                                                             \
    /* PV(t) */                                                                   \
    _Pragma("unroll") for (int t = 0; t < 4; ++t) {                               \
      o[t] = MFMA(vfr[2 * t], pfrag0, o[t]);                                      \
      o[t] = MFMA(vfr[2 * t + 1], pfrag1, o[t]);                                  \
    }                                                                             \
    o5 = MFMA(ones, pfrag0, o5);                                                  \
    o5 = MFMA(ones, pfrag1, o5);                                                  \
    __builtin_amdgcn_s_setprio(0);                                                \
  }

  for (int kb2 = 0; kb2 < NT; kb2 += 2) {
    STEP(mwa, mwb, kb2);
    STEP(mwb, mwa, kb2 + 1);
  }
#undef STEP

  const float inv = 1.0f / o5[0];
  float* orow = out + ((size_t)b * S_LEN + qrow) * E_DIM + h * HD;
#pragma unroll
  for (int t = 0; t < 4; ++t) {
    f32x4 v;
#pragma unroll
    for (int r = 0; r < 4; ++r) v[r] = o[t][r] * inv;
    *(f32x4*)(orow + 16 * t + 4 * g) = v;
  }
}

extern "C" void kernel_launch(void* const* d_in, const int* in_sizes, int n_in,
                              void* d_out, int out_size, void* d_ws, size_t ws_size,
                              hipStream_t stream) {
  const float* Q = (const float*)d_in[0];
  const float* K = (const float*)d_in[1];
  const float* V = (const float*)d_in[2];
  const int* mask = (const int*)d_in[3];
  const float* Wq = (const float*)d_in[4];
  const float* bq = (const float*)d_in[5];
  const float* Wk = (const float*)d_in[6];
  const float* bk = (const float*)d_in[7];
  const float* Wv = (const float*)d_in[8];
  const float* bv = (const float*)d_in[9];
  float* out = (float*)d_out;

  char* ws = (char*)d_ws;
  const size_t proj_bytes = (size_t)2 * NH * S_LEN * HD * 2;  // 8 MB each (B=2)
  bf16* KpF = (bf16*)ws;
  bf16* VpF = (bf16*)(ws + proj_bytes);
  u64* mbits = (u64*)(ws + 2 * proj_bytes);      // 512 KB

  kvproj_k<<<2 * NH * (S_LEN / 64), 256, 0, stream>>>(K, V, Wk, bk, Wv, bv, mask,
                                                      KpF, VpF, mbits);
  attn_k<<<2 * NH * (S_LEN / 64), 256, 0, stream>>>(Q, Wq, bq, KpF, VpF, mbits, out);
}

// Round 7
// 137.703 us; speedup vs baseline: 1.0919x; 1.0919x over previous
//
#include <hip/hip_runtime.h>

#define S_LEN 2048
#define E_DIM 1024
#define NH 16
#define HD 64
#define NT (S_LEN / 64)
#define NTW (NT / 4)   // K-tiles per wave (split-K across 4 waves)
// (1/sqrt(64)) * log2(e): fold softmax scale into log2 domain (applied to Q pre-cvt)
#define SCALE_L2E 0.18033688011112042f
#define DEFER_THR 8.0f

typedef __bf16 bf16;
typedef __attribute__((ext_vector_type(4))) bf16 bf16x4;
typedef __attribute__((ext_vector_type(8))) bf16 bf16x8;
typedef __attribute__((ext_vector_type(4))) float f32x4;
typedef unsigned long long u64;
typedef unsigned int u32;

#define MFMA(a, b, c) __builtin_amdgcn_mfma_f32_16x16x32_bf16((a), (b), (c), 0, 0, 0)

__device__ __forceinline__ bf16x8 cvt8(f32x4 a, f32x4 b) {
  bf16x8 r;
  r[0] = (bf16)a[0]; r[1] = (bf16)a[1]; r[2] = (bf16)a[2]; r[3] = (bf16)a[3];
  r[4] = (bf16)b[0]; r[5] = (bf16)b[1]; r[6] = (bf16)b[2]; r[7] = (bf16)b[3];
  return r;
}

__device__ __forceinline__ bf16x8 load_cvt_frag(const float* p) {
  f32x4 a = *(const f32x4*)(p);
  f32x4 b = *(const f32x4*)(p + 16);
  return cvt8(a, b);
}

// ---------------- K/V projection + fused mask bit-pack (validated in R6) ----------------
__global__ __launch_bounds__(256) void kvproj_k(
    const float* __restrict__ Kin, const float* __restrict__ Vin,
    const float* __restrict__ Wk, const float* __restrict__ bk,
    const float* __restrict__ Wv, const float* __restrict__ bv,
    const int* __restrict__ mask,
    bf16* __restrict__ KpF, bf16* __restrict__ VpF, u64* __restrict__ bits) {
  const int xcd = blockIdx.x & 7;
  const int idx = blockIdx.x >> 3;           // 0..127
  const int bh = xcd * 4 + (idx >> 5);       // 4 heads per XCD
  const int sblk = idx & 31;                 // S/64 = 32
  const int h = bh & (NH - 1);
  const int b = bh >> 4;
  const int lane = threadIdx.x & 63;
  const int wave = threadIdx.x >> 6;
  const int g = lane >> 4;
  const int c16 = lane & 15;
  const int sbase = sblk * 64 + wave * 16;
  const int srow = sbase + c16;

  const float* xk = Kin + ((size_t)b * S_LEN + srow) * E_DIM + h * HD;
  const float* xv = Vin + ((size_t)b * S_LEN + srow) * E_DIM + h * HD;
  bf16x8 xkf[2], xvf[2];
#pragma unroll
  for (int c = 0; c < 2; ++c) {
    xkf[c] = load_cvt_frag(xk + 32 * c + 4 * g);
    xvf[c] = load_cvt_frag(xv + 32 * c + 4 * g);
  }

  // Kp = Xk * Wk^T + bk
#pragma unroll
  for (int nt = 0; nt < 4; ++nt) {
    const float* wr = Wk + (16 * nt + c16) * HD + 4 * g;
    f32x4 acc = {0.f, 0.f, 0.f, 0.f};
    acc = MFMA(xkf[0], load_cvt_frag(wr), acc);
    acc = MFMA(xkf[1], load_cvt_frag(wr + 32), acc);
    const float bias = bk[16 * nt + c16];
    const size_t fidx = (((size_t)bh * 32 + sblk) * 4 + wave) * 2 + (nt >> 1);
    const int e = (c16 & 3) + 4 * (nt & 1);
#pragma unroll
    for (int r = 0; r < 4; ++r) {
      const int lane_p = (c16 >> 2) * 16 + 4 * g + r;
      KpF[fidx * 512 + lane_p * 8 + e] = (bf16)(acc[r] + bias);
    }
  }
  // Vp (transposed): A = Wv rows=d_out, B = Xv^T
#pragma unroll
  for (int nt = 0; nt < 4; ++nt) {
    const float* wr = Wv + (16 * nt + c16) * HD + 4 * g;
    f32x4 acc = {0.f, 0.f, 0.f, 0.f};
    acc = MFMA(load_cvt_frag(wr), xvf[0], acc);
    acc = MFMA(load_cvt_frag(wr + 32), xvf[1], acc);
    const size_t fidx = (((size_t)bh * 32 + sblk) * 4 + nt) * 2 + (wave >> 1);
    const int e = (c16 & 3) + 4 * (wave & 1);
#pragma unroll
    for (int r = 0; r < 4; ++r) {
      const int dout = 16 * nt + 4 * g + r;
      const int lane_p = (c16 >> 2) * 16 + 4 * g + r;
      VpF[fidx * 512 + lane_p * 8 + e] = (bf16)(acc[r] + bv[dout]);
    }
  }

  // fused mask bit-pack: this block handles 64 words, 16 per wave
  const int wbase = blockIdx.x * 64 + wave * 16;
  int mv[16];
#pragma unroll
  for (int i = 0; i < 16; ++i) mv[i] = mask[(size_t)(wbase + i) * 64 + lane];
#pragma unroll
  for (int i = 0; i < 16; ++i) {
    const u64 bb = __ballot(mv[i] != 0);
    const int w = wbase + i;  // w = row*32 + colblk
    if (lane == 0) bits[(size_t)(w & 31) * S_LEN + (w >> 5)] = bb;
  }
}

// ---------------- attention: split-K flash (4 waves x 8 tiles) + LDS merge ----------------
// Block = one 16-q-row group. Wave w processes K-tiles [8w, 8w+8) into flash
// partials (o, l, m); one barrier; log-sum-exp merge; wave w writes d-block w.
__global__ __launch_bounds__(256) void attn_k(
    const float* __restrict__ Qin, const float* __restrict__ Wq, const float* __restrict__ bq,
    const bf16* __restrict__ KpF, const bf16* __restrict__ VpF,
    const u64* __restrict__ mbits, float* __restrict__ out) {
  const int xcd = blockIdx.x & 7;
  const int idx = blockIdx.x >> 3;         // 0..511
  const int bh = xcd * 4 + (idx >> 7);     // 4 heads per XCD
  const int qg = idx & 127;                // q-group (16 rows) 0..127
  const int h = bh & (NH - 1);
  const int b = bh >> 4;
  const int lane = threadIdx.x & 63;
  const int wave = threadIdx.x >> 6;
  const int g = lane >> 4;
  const int c16 = lane & 15;
  const int qrow = qg * 16 + c16;          // each lane owns ONE q row

  __shared__ float sm_m[4][16];
  __shared__ float sm_l[4][16];
  __shared__ float sm_o[4][16][65];        // 65: bank-conflict-free column reads

  // Q projection in-register (all 4 waves compute the same 16 rows; cheap).
  const float* xq = Qin + ((size_t)b * S_LEN + qrow) * E_DIM + h * HD;
  bf16x8 xqf[2];
#pragma unroll
  for (int c = 0; c < 2; ++c) xqf[c] = load_cvt_frag(xq + 32 * c + 4 * g);
  f32x4 qt[4];
#pragma unroll
  for (int t = 0; t < 4; ++t) {
    const float* wr = Wq + (16 * t + c16) * HD + 4 * g;
    f32x4 acc = {0.f, 0.f, 0.f, 0.f};
    acc = MFMA(load_cvt_frag(wr), xqf[0], acc);
    acc = MFMA(load_cvt_frag(wr + 32), xqf[1], acc);
#pragma unroll
    for (int r = 0; r < 4; ++r) acc[r] = (acc[r] + bq[16 * t + 4 * g + r]) * SCALE_L2E;
    qt[t] = acc;
  }
  bf16x8 qfrag[2];
#pragma unroll
  for (int c = 0; c < 2; ++c) qfrag[c] = cvt8(qt[2 * c], qt[2 * c + 1]);

  bf16x8 ones;
#pragma unroll
  for (int i = 0; i < 8; ++i) ones[i] = (bf16)1.0f;

  // per-lane fragment bases; this wave's tile span starts at kb0 = 8*wave
  const int kb0 = wave * NTW;
  const bf16* ktl = KpF + (((size_t)bh * 32 + kb0) * 4096) + lane * 8;
  const bf16* vtl = VpF + (((size_t)bh * 32 + kb0) * 4096) + lane * 8;
  const u64* mrowT = mbits + (size_t)kb0 * S_LEN + qrow;  // + i*S_LEN within span

  float m = -1e30f;
  f32x4 o[4] = {};
  f32x4 o5 = {};

  bf16x8 kfa[8], kfb[8], vfr[8];
  u64 mwa, mwb;

  // prologue: first tile of this wave's span
#pragma unroll
  for (int f = 0; f < 8; ++f) kfa[f] = *(const bf16x8*)(ktl + f * 512);
  mwa = mrowT[0];

#define PROCESS(CURK, NXTK, MWC, MWN, IT)                                         \
  {                                                                               \
    const int nk = ((IT) + 1 < NTW) ? (IT) + 1 : NTW - 1;                         \
    _Pragma("unroll") for (int f = 0; f < 8; ++f)                                 \
        NXTK[f] = *(const bf16x8*)(ktl + (size_t)nk * 4096 + f * 512);            \
    MWN = mrowT[(size_t)nk * S_LEN];                                              \
    _Pragma("unroll") for (int f = 0; f < 8; ++f)                                 \
        vfr[f] = *(const bf16x8*)(vtl + (size_t)(IT) * 4096 + f * 512);           \
    f32x4 st[4];                                                                  \
    __builtin_amdgcn_s_setprio(1);                                                \
    _Pragma("unroll") for (int ks = 0; ks < 4; ++ks) {                            \
      f32x4 acc = {0.f, 0.f, 0.f, 0.f};                                           \
      acc = MFMA(CURK[2 * ks], qfrag[0], acc);                                    \
      acc = MFMA(CURK[2 * ks + 1], qfrag[1], acc);                                \
      st[ks] = acc;                                                               \
    }                                                                             \
    __builtin_amdgcn_s_setprio(0);                                                \
    const u64 mws = (MWC) >> (4 * g);                                             \
    const u32 mlo = (u32)mws;                                                     \
    const u32 mhi = (u32)(mws >> 32);                                             \
    const float t0 = fmaxf(fmaxf(st[0][0], st[0][1]), st[0][2]);                  \
    const float t1 = fmaxf(fmaxf(st[0][3], st[1][0]), st[1][1]);                  \
    const float t2 = fmaxf(fmaxf(st[1][2], st[1][3]), st[2][0]);                  \
    const float t3 = fmaxf(fmaxf(st[2][1], st[2][2]), st[2][3]);                  \
    const float t4 = fmaxf(fmaxf(st[3][0], st[3][1]), st[3][2]);                  \
    const float tm =                                                              \
        fmaxf(fmaxf(fmaxf(t0, t1), t2), fmaxf(fmaxf(t3, t4), st[3][3]));          \
    if (!__all(tm <= m + DEFER_THR)) {                                            \
      float tmax = fmaxf(tm, __shfl_xor(tm, 16));                                 \
      tmax = fmaxf(tmax, __shfl_xor(tmax, 32));                                   \
      const float mnew = fmaxf(m, tmax);                                          \
      const float corr = __builtin_amdgcn_exp2f(m - mnew);                        \
      _Pragma("unroll") for (int t = 0; t < 4; ++t)                               \
          _Pragma("unroll") for (int r = 0; r < 4; ++r) o[t][r] *= corr;          \
      _Pragma("unroll") for (int r = 0; r < 4; ++r) o5[r] *= corr;                \
      m = mnew;                                                                   \
    }                                                                             \
    _Pragma("unroll") for (int ks = 0; ks < 4; ++ks) {                            \
      const u32 mword = (ks < 2) ? mlo : mhi;                                     \
      const int base = (ks & 1) * 16;                                             \
      _Pragma("unroll") for (int r = 0; r < 4; ++r) {                             \
        const float p = __builtin_amdgcn_exp2f(st[ks][r] - m);                    \
        const int keep = __builtin_amdgcn_sbfe(mword, base + r, 1);               \
        st[ks][r] = __uint_as_float(__float_as_uint(p) & (u32)keep);              \
      }                                                                           \
    }                                                                             \
    const bf16x8 pfrag0 = cvt8(st[0], st[1]);                                     \
    const bf16x8 pfrag1 = cvt8(st[2], st[3]);                                     \
    __builtin_amdgcn_s_setprio(1);                                                \
    _Pragma("unroll") for (int t = 0; t < 4; ++t) {                               \
      o[t] = MFMA(vfr[2 * t], pfrag0, o[t]);                                      \
      o[t] = MFMA(vfr[2 * t + 1], pfrag1, o[t]);                                  \
    }                                                                             \
    o5 = MFMA(ones, pfrag0, o5);                                                  \
    o5 = MFMA(ones, pfrag1, o5);                                                  \
    __builtin_amdgcn_s_setprio(0);                                                \
  }

#pragma unroll
  for (int i2 = 0; i2 < NTW; i2 += 2) {
    PROCESS(kfa, kfb, mwa, mwb, i2);
    PROCESS(kfb, kfa, mwb, mwa, i2 + 1);
  }
#undef PROCESS

  // ---- stage partials (m, l uniform across g; o distinct per (g,t,r)) ----
  if (g == 0) {
    sm_m[wave][c16] = m;
    sm_l[wave][c16] = o5[0];
  }
#pragma unroll
  for (int t = 0; t < 4; ++t)
#pragma unroll
    for (int r = 0; r < 4; ++r) sm_o[wave][c16][16 * t + 4 * g + r] = o[t][r];
  __syncthreads();

  // ---- merge: wave w produces d-block w for all 16 rows ----
  const float m0 = sm_m[0][c16], m1 = sm_m[1][c16];
  const float m2 = sm_m[2][c16], m3 = sm_m[3][c16];
  const float M = fmaxf(fmaxf(m0, m1), fmaxf(m2, m3));
  const float c0 = __builtin_amdgcn_exp2f(m0 - M);
  const float c1 = __builtin_amdgcn_exp2f(m1 - M);
  const float c2 = __builtin_amdgcn_exp2f(m2 - M);
  const float c3 = __builtin_amdgcn_exp2f(m3 - M);
  const float lsum = c0 * sm_l[0][c16] + c1 * sm_l[1][c16] +
                     c2 * sm_l[2][c16] + c3 * sm_l[3][c16];
  const float inv = 1.0f / lsum;
  const int dbase = 16 * wave + 4 * g;
  f32x4 v;
#pragma unroll
  for (int r = 0; r < 4; ++r) {
    const float s = c0 * sm_o[0][c16][dbase + r] + c1 * sm_o[1][c16][dbase + r] +
                    c2 * sm_o[2][c16][dbase + r] + c3 * sm_o[3][c16][dbase + r];
    v[r] = s * inv;
  }
  float* orow = out + ((size_t)b * S_LEN + qrow) * E_DIM + h * HD;
  *(f32x4*)(orow + dbase) = v;
}

extern "C" void kernel_launch(void* const* d_in, const int* in_sizes, int n_in,
                              void* d_out, int out_size, void* d_ws, size_t ws_size,
                              hipStream_t stream) {
  const float* Q = (const float*)d_in[0];
  const float* K = (const float*)d_in[1];
  const float* V = (const float*)d_in[2];
  const int* mask = (const int*)d_in[3];
  const float* Wq = (const float*)d_in[4];
  const float* bq = (const float*)d_in[5];
  const float* Wk = (const float*)d_in[6];
  const float* bk = (const float*)d_in[7];
  const float* Wv = (const float*)d_in[8];
  const float* bv = (const float*)d_in[9];
  float* out = (float*)d_out;

  char* ws = (char*)d_ws;
  const size_t proj_bytes = (size_t)2 * NH * S_LEN * HD * 2;  // 8 MB each (B=2)
  bf16* KpF = (bf16*)ws;
  bf16* VpF = (bf16*)(ws + proj_bytes);
  u64* mbits = (u64*)(ws + 2 * proj_bytes);      // 512 KB

  kvproj_k<<<2 * NH * (S_LEN / 64), 256, 0, stream>>>(K, V, Wk, bk, Wv, bv, mask,
                                                      KpF, VpF, mbits);
  attn_k<<<2 * NH * (S_LEN / 16), 256, 0, stream>>>(Q, Wq, bq, KpF, VpF, mbits, out);
}

// Round 8
// 96.097 us; speedup vs baseline: 1.5647x; 1.4330x over previous
//
#include <hip/hip_runtime.h>

#define S_LEN 2048
#define E_DIM 1024
#define NH 16
#define HD 64
#define NT (S_LEN / 64)
// (1/sqrt(64)) * log2(e): fold softmax scale into log2 domain (applied to Q pre-cvt)
#define SCALE_L2E 0.18033688011112042f
#define DEFER_THR 8.0f

typedef __bf16 bf16;
typedef __attribute__((ext_vector_type(4))) bf16 bf16x4;
typedef __attribute__((ext_vector_type(8))) bf16 bf16x8;
typedef __attribute__((ext_vector_type(4))) float f32x4;
typedef unsigned long long u64;
typedef unsigned int u32;

#define MFMA(a, b, c) __builtin_amdgcn_mfma_f32_16x16x32_bf16((a), (b), (c), 0, 0, 0)

__device__ __forceinline__ bf16x8 cvt8(f32x4 a, f32x4 b) {
  bf16x8 r;
  r[0] = (bf16)a[0]; r[1] = (bf16)a[1]; r[2] = (bf16)a[2]; r[3] = (bf16)a[3];
  r[4] = (bf16)b[0]; r[5] = (bf16)b[1]; r[6] = (bf16)b[2]; r[7] = (bf16)b[3];
  return r;
}

__device__ __forceinline__ bf16x8 load_cvt_frag(const float* p) {
  f32x4 a = *(const f32x4*)(p);
  f32x4 b = *(const f32x4*)(p + 16);
  return cvt8(a, b);
}

// ---------------- K/V projection + fused mask bit-pack (validated R6/R7) ----------------
__global__ __launch_bounds__(256) void kvproj_k(
    const float* __restrict__ Kin, const float* __restrict__ Vin,
    const float* __restrict__ Wk, const float* __restrict__ bk,
    const float* __restrict__ Wv, const float* __restrict__ bv,
    const int* __restrict__ mask,
    bf16* __restrict__ KpF, bf16* __restrict__ VpF, u64* __restrict__ bits) {
  const int xcd = blockIdx.x & 7;
  const int idx = blockIdx.x >> 3;           // 0..127
  const int bh = xcd * 4 + (idx >> 5);       // 4 heads per XCD
  const int sblk = idx & 31;                 // S/64 = 32
  const int h = bh & (NH - 1);
  const int b = bh >> 4;
  const int lane = threadIdx.x & 63;
  const int wave = threadIdx.x >> 6;
  const int g = lane >> 4;
  const int c16 = lane & 15;
  const int sbase = sblk * 64 + wave * 16;
  const int srow = sbase + c16;

  const float* xk = Kin + ((size_t)b * S_LEN + srow) * E_DIM + h * HD;
  const float* xv = Vin + ((size_t)b * S_LEN + srow) * E_DIM + h * HD;
  bf16x8 xkf[2], xvf[2];
#pragma unroll
  for (int c = 0; c < 2; ++c) {
    xkf[c] = load_cvt_frag(xk + 32 * c + 4 * g);
    xvf[c] = load_cvt_frag(xv + 32 * c + 4 * g);
  }

  // Kp = Xk * Wk^T + bk
#pragma unroll
  for (int nt = 0; nt < 4; ++nt) {
    const float* wr = Wk + (16 * nt + c16) * HD + 4 * g;
    f32x4 acc = {0.f, 0.f, 0.f, 0.f};
    acc = MFMA(xkf[0], load_cvt_frag(wr), acc);
    acc = MFMA(xkf[1], load_cvt_frag(wr + 32), acc);
    const float bias = bk[16 * nt + c16];
    const size_t fidx = (((size_t)bh * 32 + sblk) * 4 + wave) * 2 + (nt >> 1);
    const int e = (c16 & 3) + 4 * (nt & 1);
#pragma unroll
    for (int r = 0; r < 4; ++r) {
      const int lane_p = (c16 >> 2) * 16 + 4 * g + r;
      KpF[fidx * 512 + lane_p * 8 + e] = (bf16)(acc[r] + bias);
    }
  }
  // Vp (transposed): A = Wv rows=d_out, B = Xv^T
#pragma unroll
  for (int nt = 0; nt < 4; ++nt) {
    const float* wr = Wv + (16 * nt + c16) * HD + 4 * g;
    f32x4 acc = {0.f, 0.f, 0.f, 0.f};
    acc = MFMA(load_cvt_frag(wr), xvf[0], acc);
    acc = MFMA(load_cvt_frag(wr + 32), xvf[1], acc);
    const size_t fidx = (((size_t)bh * 32 + sblk) * 4 + nt) * 2 + (wave >> 1);
    const int e = (c16 & 3) + 4 * (wave & 1);
#pragma unroll
    for (int r = 0; r < 4; ++r) {
      const int dout = 16 * nt + 4 * g + r;
      const int lane_p = (c16 >> 2) * 16 + 4 * g + r;
      VpF[fidx * 512 + lane_p * 8 + e] = (bf16)(acc[r] + bv[dout]);
    }
  }

  // fused mask bit-pack: this block handles 64 words, 16 per wave
  const int wbase = blockIdx.x * 64 + wave * 16;
  int mv[16];
#pragma unroll
  for (int i = 0; i < 16; ++i) mv[i] = mask[(size_t)(wbase + i) * 64 + lane];
#pragma unroll
  for (int i = 0; i < 16; ++i) {
    const u64 bb = __ballot(mv[i] != 0);
    const int w = wbase + i;  // w = row*32 + colblk
    if (lane == 0) bits[(size_t)(w & 31) * S_LEN + (w >> 5)] = bb;
  }
}

// ---------------- attention: barrier-free, 32 q-rows/wave (2 q-groups) ----------------
// Each wave owns 32 q-rows; every K/V fragment load feeds TWO QK/PV passes,
// halving memory-path lines per FLOP (the R5/R7-measured bottleneck).
__global__ __launch_bounds__(256) void attn_k(
    const float* __restrict__ Qin, const float* __restrict__ Wq, const float* __restrict__ bq,
    const bf16* __restrict__ KpF, const bf16* __restrict__ VpF,
    const u64* __restrict__ mbits, float* __restrict__ out) {
  const int xcd = blockIdx.x & 7;
  const int idx = blockIdx.x >> 3;       // 0..63
  const int bh = xcd * 4 + (idx >> 4);   // 4 heads per XCD
  const int qg4 = idx & 15;              // group-of-4 q-groups
  const int h = bh & (NH - 1);
  const int b = bh >> 4;
  const int lane = threadIdx.x & 63;
  const int wave = threadIdx.x >> 6;
  const int g = lane >> 4;
  const int c16 = lane & 15;
  const int qbase = (qg4 * 4 + wave) * 32;   // this wave's 32 q-rows

  // Q projection in-register for both 16-row groups; scale folded pre-cvt.
  bf16x8 qfrag[2][2];
#pragma unroll
  for (int grp = 0; grp < 2; ++grp) {
    const int qrow = qbase + grp * 16 + c16;
    const float* xq = Qin + ((size_t)b * S_LEN + qrow) * E_DIM + h * HD;
    bf16x8 xqf[2];
#pragma unroll
    for (int c = 0; c < 2; ++c) xqf[c] = load_cvt_frag(xq + 32 * c + 4 * g);
    f32x4 qt[4];
#pragma unroll
    for (int t = 0; t < 4; ++t) {
      const float* wr = Wq + (16 * t + c16) * HD + 4 * g;
      f32x4 acc = {0.f, 0.f, 0.f, 0.f};
      acc = MFMA(load_cvt_frag(wr), xqf[0], acc);
      acc = MFMA(load_cvt_frag(wr + 32), xqf[1], acc);
#pragma unroll
      for (int r = 0; r < 4; ++r) acc[r] = (acc[r] + bq[16 * t + 4 * g + r]) * SCALE_L2E;
      qt[t] = acc;
    }
    qfrag[grp][0] = cvt8(qt[0], qt[1]);
    qfrag[grp][1] = cvt8(qt[2], qt[3]);
  }

  bf16x8 ones;
#pragma unroll
  for (int i = 0; i < 8; ++i) ones[i] = (bf16)1.0f;

  // per-lane fragment bases (16B/lane, fully coalesced)
  const bf16* ktl = KpF + ((size_t)bh * 32) * 4096 + lane * 8;  // + kb*4096 + f*512
  const bf16* vtl = VpF + ((size_t)bh * 32) * 4096 + lane * 8;
  const u64* mrowA = mbits + (qbase + c16);        // + kb*S_LEN
  const u64* mrowB = mrowA + 16;

  float m[2] = {-1e30f, -1e30f};
  f32x4 o[2][4] = {};
  f32x4 o5[2] = {};

  bf16x8 kfa[8], kfb[8], vfr[8];
  u64 mca[2], mcb[2];

  // prologue: tile 0 K-frags + mask words
#pragma unroll
  for (int f = 0; f < 8; ++f) kfa[f] = *(const bf16x8*)(ktl + f * 512);
  mca[0] = mrowA[0];
  mca[1] = mrowB[0];

  // one tile: issue next-K/next-mask + cur-V; per group: QK -> softmax -> PV
#define PROCESS(CURK, NXTK, MWC, MWN, KBT)                                        \
  {                                                                               \
    const int nk = ((KBT) + 1 < NT) ? (KBT) + 1 : NT - 1;                         \
    _Pragma("unroll") for (int f = 0; f < 8; ++f)                                 \
        NXTK[f] = *(const bf16x8*)(ktl + (size_t)nk * 4096 + f * 512);            \
    MWN[0] = mrowA[(size_t)nk * S_LEN];                                           \
    MWN[1] = mrowB[(size_t)nk * S_LEN];                                           \
    _Pragma("unroll") for (int f = 0; f < 8; ++f)                                 \
        vfr[f] = *(const bf16x8*)(vtl + (size_t)(KBT) * 4096 + f * 512);          \
    _Pragma("unroll") for (int grp = 0; grp < 2; ++grp) {                         \
      f32x4 st[4];                                                                \
      __builtin_amdgcn_s_setprio(1);                                              \
      _Pragma("unroll") for (int ks = 0; ks < 4; ++ks) {                          \
        f32x4 acc = {0.f, 0.f, 0.f, 0.f};                                         \
        acc = MFMA(CURK[2 * ks], qfrag[grp][0], acc);                             \
        acc = MFMA(CURK[2 * ks + 1], qfrag[grp][1], acc);                         \
        st[ks] = acc;                                                             \
      }                                                                           \
      __builtin_amdgcn_s_setprio(0);                                              \
      const u64 mws = MWC[grp] >> (4 * g);                                        \
      const u32 mlo = (u32)mws;                                                   \
      const u32 mhi = (u32)(mws >> 32);                                           \
      const float t0 = fmaxf(fmaxf(st[0][0], st[0][1]), st[0][2]);                \
      const float t1 = fmaxf(fmaxf(st[0][3], st[1][0]), st[1][1]);                \
      const float t2 = fmaxf(fmaxf(st[1][2], st[1][3]), st[2][0]);                \
      const float t3 = fmaxf(fmaxf(st[2][1], st[2][2]), st[2][3]);                \
      const float t4 = fmaxf(fmaxf(st[3][0], st[3][1]), st[3][2]);                \
      const float tm =                                                            \
          fmaxf(fmaxf(fmaxf(t0, t1), t2), fmaxf(fmaxf(t3, t4), st[3][3]));        \
      if (!__all(tm <= m[grp] + DEFER_THR)) {                                     \
        float tmax = fmaxf(tm, __shfl_xor(tm, 16));                               \
        tmax = fmaxf(tmax, __shfl_xor(tmax, 32));                                 \
        const float mnew = fmaxf(m[grp], tmax);                                   \
        const float corr = __builtin_amdgcn_exp2f(m[grp] - mnew);                 \
        _Pragma("unroll") for (int t = 0; t < 4; ++t)                             \
            _Pragma("unroll") for (int r = 0; r < 4; ++r) o[grp][t][r] *= corr;   \
        _Pragma("unroll") for (int r = 0; r < 4; ++r) o5[grp][r] *= corr;         \
        m[grp] = mnew;                                                            \
      }                                                                           \
      _Pragma("unroll") for (int ks = 0; ks < 4; ++ks) {                          \
        const u32 mword = (ks < 2) ? mlo : mhi;                                   \
        const int base = (ks & 1) * 16;                                           \
        _Pragma("unroll") for (int r = 0; r < 4; ++r) {                           \
          const float p = __builtin_amdgcn_exp2f(st[ks][r] - m[grp]);             \
          const int keep = __builtin_amdgcn_sbfe(mword, base + r, 1);             \
          st[ks][r] = __uint_as_float(__float_as_uint(p) & (u32)keep);            \
        }                                                                         \
      }                                                                           \
      const bf16x8 pfrag0 = cvt8(st[0], st[1]);                                   \
      const bf16x8 pfrag1 = cvt8(st[2], st[3]);                                   \
      __builtin_amdgcn_s_setprio(1);                                              \
      _Pragma("unroll") for (int t = 0; t < 4; ++t) {                             \
        o[grp][t] = MFMA(vfr[2 * t], pfrag0, o[grp][t]);                          \
        o[grp][t] = MFMA(vfr[2 * t + 1], pfrag1, o[grp][t]);                      \
      }                                                                           \
      o5[grp] = MFMA(ones, pfrag0, o5[grp]);                                      \
      o5[grp] = MFMA(ones, pfrag1, o5[grp]);                                      \
      __builtin_amdgcn_s_setprio(0);                                              \
    }                                                                             \
  }

  for (int kb2 = 0; kb2 < NT; kb2 += 2) {
    PROCESS(kfa, kfb, mca, mcb, kb2);
    PROCESS(kfb, kfa, mcb, mca, kb2 + 1);
  }
#undef PROCESS

#pragma unroll
  for (int grp = 0; grp < 2; ++grp) {
    const float inv = 1.0f / o5[grp][0];
    float* orow = out + ((size_t)b * S_LEN + qbase + grp * 16 + c16) * E_DIM + h * HD;
#pragma unroll
    for (int t = 0; t < 4; ++t) {
      f32x4 v;
#pragma unroll
      for (int r = 0; r < 4; ++r) v[r] = o[grp][t][r] * inv;
      *(f32x4*)(orow + 16 * t + 4 * g) = v;
    }
  }
}

extern "C" void kernel_launch(void* const* d_in, const int* in_sizes, int n_in,
                              void* d_out, int out_size, void* d_ws, size_t ws_size,
                              hipStream_t stream) {
  const float* Q = (const float*)d_in[0];
  const float* K = (const float*)d_in[1];
  const float* V = (const float*)d_in[2];
  const int* mask = (const int*)d_in[3];
  const float* Wq = (const float*)d_in[4];
  const float* bq = (const float*)d_in[5];
  const float* Wk = (const float*)d_in[6];
  const float* bk = (const float*)d_in[7];
  const float* Wv = (const float*)d_in[8];
  const float* bv = (const float*)d_in[9];
  float* out = (float*)d_out;

  char* ws = (char*)d_ws;
  const size_t proj_bytes = (size_t)2 * NH * S_LEN * HD * 2;  // 8 MB each (B=2)
  bf16* KpF = (bf16*)ws;
  bf16* VpF = (bf16*)(ws + proj_bytes);
  u64* mbits = (u64*)(ws + 2 * proj_bytes);      // 512 KB

  kvproj_k<<<2 * NH * (S_LEN / 64), 256, 0, stream>>>(K, V, Wk, bk, Wv, bv, mask,
                                                      KpF, VpF, mbits);
  // 512 blocks: 2048 waves, one 32-q-row group each
  attn_k<<<2 * NH * (S_LEN / 128), 256, 0, stream>>>(Q, Wq, bq, KpF, VpF, mbits, out);
}